// Round 9
// baseline (93.177 us; speedup 1.0000x reference)
//
#include <hip/hip_runtime.h>
#include <hip/hip_bf16.h>
#include <stdint.h>

// BERT self-attention fwd: B=2, S=2048, D=768, H=12, W=64. f32 in/out, bf16 MFMA inside.
// Stage 1: cvt x,Wq,Wk,Wv -> bf16.
// Stage 2: QKV projection GEMM (unchanged core). Epilogue now writes K and V in
//   FRAGMENT-MAJOR layouts so attention can load MFMA fragments with coalesced
//   per-wave global loads (no LDS, no barriers in the K-loop):
//   K'[bh][kt][ds][lane][j]: elem = K[key=kt*32+(lane&31)][d=16ds+8(lane>>5)+j]
//   V'[bh][kt][wh][sp][lane][j]: elem = V[key=kt*32+16sp+8(lane>>5)+j][w=wh*32+(lane&31)]
// Stage 3: flash attention, BARRIER-FREE K-loop: each wave owns (32 q) x (wk half of keys),
//   streams K'/V' global->VGPR (K prefetch post-QK, V issued at iter top), swapped QK^T,
//   no-max softmax, in-register P via cvt_pk+permlane32_swap, scalar per-lane row-sum,
//   ballots in a register via readlane. LDS only for the epilogue cross-wk reduce (17KB).

typedef __attribute__((ext_vector_type(8))) short bf16x8;    // 8 bf16 = 4 VGPR (MFMA A/B frag)
typedef __attribute__((ext_vector_type(4))) float f32x4;     // 16x16 MFMA C/D frag
typedef __attribute__((ext_vector_type(16))) float f32x16;   // 32x32 MFMA C/D frag
typedef __attribute__((ext_vector_type(8))) unsigned short u16x8;

#define MFMA16(a, b, c) __builtin_amdgcn_mfma_f32_16x16x32_bf16((a), (b), (c), 0, 0, 0)
#define MFMA32(a, b, c) __builtin_amdgcn_mfma_f32_32x32x16_bf16((a), (b), (c), 0, 0, 0)
#define SWZ(row, colb) ((colb) ^ (((row) & 7) << 4))  // 128B-row swizzle (epilogue only)

union U32x4BF {
  unsigned u[4];
  bf16x8 v;
};

__device__ __forceinline__ void gl_lds16(const void* g, void* l) {
  __builtin_amdgcn_global_load_lds(
      (__attribute__((address_space(1))) void*)const_cast<void*>(g),
      (__attribute__((address_space(3))) void*)l, 16, 0, 0);
}

__device__ __forceinline__ unsigned short f2bf(float x) {  // RNE f32->bf16
  unsigned int v = __float_as_uint(x);
  return (unsigned short)((v + 0x7fffu + ((v >> 16) & 1u)) >> 16);
}

// ---------------- Stage 1: f32 -> bf16 convert ----------------
__global__ __launch_bounds__(256) void cvt_all(
    const float* __restrict__ x, const float* __restrict__ wq,
    const float* __restrict__ wk, const float* __restrict__ wv,
    unsigned short* __restrict__ xb, unsigned short* __restrict__ wb) {
  int i = blockIdx.x * 256 + threadIdx.x;  // group-of-8 index; total 614400
  const float* s;
  unsigned short* d;
  int off;
  if (i < 393216)      { s = x;  d = xb;            off = i; }
  else if (i < 466944) { s = wq; d = wb;            off = i - 393216; }
  else if (i < 540672) { s = wk; d = wb + 589824;   off = i - 466944; }
  else                 { s = wv; d = wb + 1179648;  off = i - 540672; }
  const float4* sp = (const float4*)s + (size_t)off * 2;
  float4 a = sp[0], b2 = sp[1];
  u16x8 o;
  o[0] = f2bf(a.x); o[1] = f2bf(a.y); o[2] = f2bf(a.z); o[3] = f2bf(a.w);
  o[4] = f2bf(b2.x); o[5] = f2bf(b2.y); o[6] = f2bf(b2.z); o[7] = f2bf(b2.w);
  *((u16x8*)d + off) = o;
}

// ---------------- Stage 2: fused QKV projection (BK=32, 3-buf, depth-2) ----------------
__global__ __launch_bounds__(256) void proj_gemm(
    const unsigned short* __restrict__ xb, const unsigned short* __restrict__ wb,
    const float* __restrict__ bq, const float* __restrict__ bk, const float* __restrict__ bv,
    unsigned short* __restrict__ qw, unsigned short* __restrict__ kx,
    unsigned short* __restrict__ vx) {
  __shared__ __align__(16) char psmem[49152];  // 3 bufs x (A 8KB | B 8KB)
  const int t = threadIdx.x, lane = t & 63, wave = t >> 6;
  const int lo = lane & 15, hi = lane >> 4;  // hi in 0..3
  const int wr = wave >> 1, wc = wave & 1;   // 2x2 waves, 64x64 each
  const int mbase = blockIdx.x * 128;
  const int wsel = blockIdx.y / 6;
  const int nbase = (blockIdx.y % 6) * 128;
  const char* xc = (const char*)xb;
  const char* wmc = (const char*)(wb + (size_t)wsel * 589824);

  const int pp0 = t * 16, pp1 = t * 16 + 4096;
  const int ar0 = pp0 >> 7, ac0 = (pp0 & 127) ^ ((ar0 & 7) << 4);
  const int am0 = ((ac0 >> 6) << 6) + ar0, ak0 = ac0 & 63;
  const int ar1 = pp1 >> 7, ac1 = (pp1 & 127) ^ ((ar1 & 7) << 4);
  const int am1 = ((ac1 >> 6) << 6) + ar1, ak1 = ac1 & 63;

  const char* xa0 = xc + (size_t)(mbase + am0) * 1536 + ak0;
  const char* xa1 = xc + (size_t)(mbase + am1) * 1536 + ak1;
  const char* wa0 = wmc + (size_t)(nbase + am0) * 1536 + ak0;
  const char* wa1 = wmc + (size_t)(nbase + am1) * 1536 + ak1;

#define PSTAGE(BUF)                              \
  do {                                           \
    char* lb = psmem + (BUF) * 16384;            \
    gl_lds16(xa0, lb + pp0);                     \
    gl_lds16(xa1, lb + pp1);                     \
    gl_lds16(wa0, lb + 8192 + pp0);              \
    gl_lds16(wa1, lb + 8192 + pp1);              \
    xa0 += 64; xa1 += 64; wa0 += 64; wa1 += 64;  \
  } while (0)

  f32x4 acc[4][4];
#pragma unroll
  for (int i = 0; i < 4; i++)
#pragma unroll
    for (int j = 0; j < 4; j++) acc[i][j] = (f32x4){0.f, 0.f, 0.f, 0.f};

  const int axor = (lo & 7) << 4;
  PSTAGE(0);
  PSTAGE(1);
  int cur = 0, sb = 2;
#pragma unroll 1
  for (int it = 0; it < 24; ++it) {
    if (it < 22) {
      PSTAGE(sb);
      asm volatile("s_waitcnt vmcnt(8)" ::: "memory");
    } else if (it == 22) {
      asm volatile("s_waitcnt vmcnt(4)" ::: "memory");
    } else {
      asm volatile("s_waitcnt vmcnt(0)" ::: "memory");
    }
    __builtin_amdgcn_s_barrier();
    const char* lA = psmem + cur * 16384;
    const char* lB = lA + 8192;

    bf16x8 af[4], bf[4];
#pragma unroll
    for (int mf = 0; mf < 4; mf++)
      af[mf] = *(const bf16x8*)(lA + (mf * 16 + lo) * 128 + ((wr * 64 + hi * 16) ^ axor));
#pragma unroll
    for (int nf = 0; nf < 4; nf++)
      bf[nf] = *(const bf16x8*)(lB + (nf * 16 + lo) * 128 + ((wc * 64 + hi * 16) ^ axor));

    __builtin_amdgcn_s_setprio(1);
    if (wsel == 2) {  // V: operand-swapped -> acc holds C^T (rows=n, cols=m)
#pragma unroll
      for (int mf = 0; mf < 4; mf++)
#pragma unroll
        for (int nf = 0; nf < 4; nf++) acc[mf][nf] = MFMA16(bf[nf], af[mf], acc[mf][nf]);
    } else {
#pragma unroll
      for (int mf = 0; mf < 4; mf++)
#pragma unroll
        for (int nf = 0; nf < 4; nf++) acc[mf][nf] = MFMA16(af[mf], bf[nf], acc[mf][nf]);
    }
    __builtin_amdgcn_s_setprio(0);
    __builtin_amdgcn_s_barrier();  // trailing barrier: depth-2 with 3 bufs race-free
    cur = (cur == 2) ? 0 : cur + 1;
    sb = (sb == 2) ? 0 : sb + 1;
  }
#undef PSTAGE

  const float QSCALE = 0.125f * 1.44269504089f;  // fold 1/sqrt(64) * log2(e)
  if (wsel == 2) {
    // V' fragment-major: elem (key=s, w) -> kt=s>>5, wh=w>>5, sp=(s>>4)&1,
    //   lane' = (w&31) + 32*((s>>3)&1), j = s&7
#pragma unroll
    for (int nf = 0; nf < 4; nf++) {
#pragma unroll
      for (int mf = 0; mf < 4; mf++) {
#pragma unroll
        for (int r = 0; r < 4; r++) {
          int n = nbase + wc * 64 + nf * 16 + hi * 4 + r;
          int m = mbase + wr * 64 + mf * 16 + lo;
          int b_ = m >> 11, s = m & 2047;
          int h = n >> 6, w = n & 63;
          float val = acc[mf][nf][r] + bv[n];
          size_t bhh = (size_t)b_ * 12 + h;
          size_t idx = bhh * 131072 + (size_t)(s >> 5) * 2048 + (size_t)((w >> 5) & 1) * 1024 +
                       (size_t)((s >> 4) & 1) * 512 +
                       (size_t)((w & 31) + 32 * ((s >> 3) & 1)) * 8 + (s & 7);
          vx[idx] = f2bf(val);
        }
      }
    }
  } else {
    const float* bias = (wsel == 0) ? bq : bk;
#pragma unroll
    for (int nf = 0; nf < 4; nf++) {
      int n = nbase + wc * 64 + nf * 16 + lo;
      float bv_ = bias[n];
      int h = n >> 6, wcol = n & 63;
#pragma unroll
      for (int mf = 0; mf < 4; mf++) {
#pragma unroll
        for (int r = 0; r < 4; r++) {
          int m = mbase + wr * 64 + mf * 16 + hi * 4 + r;
          int b_ = m >> 11, s = m & 2047;
          float val = acc[mf][nf][r] + bv_;
          size_t bhh = (size_t)b_ * 12 + h;
          if (wsel == 0) {
            qw[(bhh * 2048 + s) * 64 + wcol] = f2bf(val * QSCALE);
          } else {
            // K' fragment-major: elem (key=s, d) -> kt=s>>5, ds=d>>4,
            //   lane' = (s&31) + 32*((d>>3)&1), j = d&7
            int d = wcol;
            size_t idx = bhh * 131072 + (size_t)(s >> 5) * 2048 + (size_t)(d >> 4) * 512 +
                         (size_t)((s & 31) + 32 * ((d >> 3) & 1)) * 8 + (d & 7);
            kx[idx] = f2bf(val);
          }
        }
      }
    }
  }
}

// ---------------- Stage 3: flash attention (barrier-free K-loop) ----------------
// grid (32, 24), block 256 = 4 waves (wq q-half x wk key-half). Each wave: 32 iters over
// its 32-key tiles (kt = wk*32 + it), streaming K'/V' fragments global->VGPR coalesced.
// Per iter: issue V(it) -> QK(it) from prefetched K regs -> prefetch K(it+1) -> softmax
// (exp2, log2e folded into Q) -> cvt_pk+permlane -> PV. No __syncthreads in the loop.
__global__ __launch_bounds__(256) void attn_kernel(
    const unsigned short* __restrict__ qw, const unsigned short* __restrict__ kx,
    const unsigned short* __restrict__ vx, const int* __restrict__ mask,
    float* __restrict__ out) {
  // [0,16384) epilogue O-staging (2 wq x 8KB) | [16384,16640) ballot bytes |
  // [16640,17152) lsum f32[128]: ((wq*32+q)*2 + wk)
  __shared__ __align__(16) char smem[17152];
  const int t = threadIdx.x, lane = t & 63, wave = t >> 6;
  const int wq = wave >> 1, wk = wave & 1;
  const int l31 = lane & 31, hl = lane >> 5;
  const int qb = blockIdx.x, bh = blockIdx.y;
  const int b = bh / 12, hh = bh - b * 12;

  // bit-pack mask: thread t packs keys [t*8, t*8+8) -> ballot bytes
  {
    const int* mb = mask + (size_t)b * 2048 + t * 8;
    int4 a0 = *(const int4*)mb;
    int4 a1 = *(const int4*)(mb + 4);
    unsigned by = (unsigned)(a0.x != 0) | ((unsigned)(a0.y != 0) << 1) |
                  ((unsigned)(a0.z != 0) << 2) | ((unsigned)(a0.w != 0) << 3) |
                  ((unsigned)(a1.x != 0) << 4) | ((unsigned)(a1.y != 0) << 5) |
                  ((unsigned)(a1.z != 0) << 6) | ((unsigned)(a1.w != 0) << 7);
    smem[16384 + t] = (char)by;
  }
  __syncthreads();
  // lane i holds the 32-key ballot of this wave's tile (i&31)
  const unsigned balv = *(const unsigned*)(smem + 16384 + (wk * 32 + l31) * 4);

  // Q B-frags: lane holds Q[q = l31 of wq-half][d = 16s + 8hl + j]
  bf16x8 qv[4];
  {
    int qrow = qb * 64 + wq * 32 + l31;
    const char* qp = (const char*)qw + ((size_t)bh * 2048 + qrow) * 128 + hl * 16;
#pragma unroll
    for (int s = 0; s < 4; s++) qv[s] = *(const bf16x8*)(qp + s * 32);
  }

  // fragment stream pointers (coalesced: lane*16 within 1KB chunks)
  const char* kp = (const char*)kx + (size_t)bh * 262144 + (size_t)wk * 131072 + lane * 16;
  const char* vp = (const char*)vx + (size_t)bh * 262144 + (size_t)wk * 131072 + lane * 16;

  f32x16 oacc[2];
#pragma unroll
  for (int wh = 0; wh < 2; wh++)
#pragma unroll
    for (int g = 0; g < 16; g++) oacc[wh][g] = 0.f;
  float lacc = 0.f;  // per-lane row-sum for q = l31 (this wave's hl/wk slice)

  // prologue: K(0) fragments
  bf16x8 ka0 = *(const bf16x8*)(kp);
  bf16x8 ka1 = *(const bf16x8*)(kp + 1024);
  bf16x8 ka2 = *(const bf16x8*)(kp + 2048);
  bf16x8 ka3 = *(const bf16x8*)(kp + 3072);
  kp += 4096;

#pragma unroll 2
  for (int it = 0; it < 32; ++it) {
    // issue V(it) early (consumed after softmax, ~300+ cyc later)
    bf16x8 v00 = *(const bf16x8*)(vp);          // wh0 sp0
    bf16x8 v01 = *(const bf16x8*)(vp + 1024);   // wh0 sp1
    bf16x8 v10 = *(const bf16x8*)(vp + 2048);   // wh1 sp0
    bf16x8 v11 = *(const bf16x8*)(vp + 3072);   // wh1 sp1
    vp += 4096;

    // QK^T swapped: sc[g] = S^T[key-in-tile = (g&3)+8(g>>2)+4hl][q = l31]
    f32x16 sc;
#pragma unroll
    for (int g = 0; g < 16; g++) sc[g] = 0.f;
    __builtin_amdgcn_s_setprio(1);
    sc = MFMA32(ka0, qv[0], sc);
    sc = MFMA32(ka1, qv[1], sc);
    sc = MFMA32(ka2, qv[2], sc);
    sc = MFMA32(ka3, qv[3], sc);
    __builtin_amdgcn_s_setprio(0);

    // prefetch K(it+1); at it=31 this harmlessly reads the adjacent V' array
    ka0 = *(const bf16x8*)(kp);
    ka1 = *(const bf16x8*)(kp + 1024);
    ka2 = *(const bf16x8*)(kp + 2048);
    ka3 = *(const bf16x8*)(kp + 3072);
    kp += 4096;

    // mask (uniform skip when all-ones)
    unsigned bal = __builtin_amdgcn_readlane(balv, it);
    if (bal != 0xFFFFFFFFu) {
#pragma unroll
      for (int g = 0; g < 16; g++) {
        int key = (g & 3) + 8 * (g >> 2) + 4 * hl;
        if (!((bal >> key) & 1)) sc[g] = -30000.f;  // exp2 -> 0
      }
    }

    // P = exp2(sc) in place; per-lane row-sum; pack to bf16 A-frags
#pragma unroll
    for (int g = 0; g < 16; g++) {
      float e_;
      asm("v_exp_f32 %0, %1" : "=v"(e_) : "v"(sc[g]));
      sc[g] = e_;
    }
    lacc += (((sc[0] + sc[1]) + (sc[2] + sc[3])) + ((sc[4] + sc[5]) + (sc[6] + sc[7]))) +
            (((sc[8] + sc[9]) + (sc[10] + sc[11])) + ((sc[12] + sc[13]) + (sc[14] + sc[15])));
    unsigned pk[4][2];
#pragma unroll
    for (int m = 0; m < 4; m++) {
      asm("v_cvt_pk_bf16_f32 %0, %1, %2" : "=v"(pk[m][0]) : "v"(sc[4 * m]), "v"(sc[4 * m + 1]));
      asm("v_cvt_pk_bf16_f32 %0, %1, %2" : "=v"(pk[m][1]) : "v"(sc[4 * m + 2]), "v"(sc[4 * m + 3]));
    }
    U32x4BF apv[2];  // A[q=l31][k_local = 16sp + 8hl + j]
#pragma unroll
    for (int sp = 0; sp < 2; sp++)
#pragma unroll
      for (int cp = 0; cp < 2; cp++) {
        unsigned xx = pk[2 * sp][cp], yy = pk[2 * sp + 1][cp];
        asm("v_permlane32_swap_b32 %0, %1" : "+v"(xx), "+v"(yy));
        apv[sp].u[cp] = xx;
        apv[sp].u[2 + cp] = yy;
      }

    // PV: oacc[wh] += P(32q x 32k) @ V(32k x 32w)
    __builtin_amdgcn_s_setprio(1);
    oacc[0] = MFMA32(apv[0].v, v00, oacc[0]);
    oacc[0] = MFMA32(apv[1].v, v01, oacc[0]);
    oacc[1] = MFMA32(apv[0].v, v10, oacc[1]);
    oacc[1] = MFMA32(apv[1].v, v11, oacc[1]);
    __builtin_amdgcn_s_setprio(0);
  }

  // ---- epilogue: cross-wk reduce of O and l, then out = O / l ----
  lacc += __shfl_xor(lacc, 32);  // combine hl halves; all lanes hold sum for q=l31 (wk half)
  if (lane < 32)
    *(float*)(smem + 16640 + (((wq * 32 + l31) << 1) + wk) * 4) = lacc;
  if (wk == 1) {  // partial O as [w][q] f32 into [0,16384)
#pragma unroll
    for (int wh = 0; wh < 2; wh++) {
      int vrow = wh * 32 + l31;
#pragma unroll
      for (int m = 0; m < 4; m++) {
        f32x4 part = (f32x4){oacc[wh][4 * m], oacc[wh][4 * m + 1],
                             oacc[wh][4 * m + 2], oacc[wh][4 * m + 3]};
        *(f32x4*)(smem + wq * 8192 + vrow * 128 + SWZ(vrow, hl * 16 + m * 32)) = part;
      }
    }
  }
  __syncthreads();
  if (wk == 0) {
    float linv[16];
#pragma unroll
    for (int g = 0; g < 16; g++) {
      int qrow = 4 * hl + (g & 3) + 8 * (g >> 2);
      float2 lp = *(const float2*)(smem + 16640 + ((wq * 32 + qrow) << 3));
      linv[g] = __builtin_amdgcn_rcpf(lp.x + lp.y);
    }
#pragma unroll
    for (int wh = 0; wh < 2; wh++) {
      int vrow = wh * 32 + l31;
#pragma unroll
      for (int m = 0; m < 4; m++) {
        f32x4 part = *(const f32x4*)(smem + wq * 8192 + vrow * 128 + SWZ(vrow, hl * 16 + m * 32));
#pragma unroll
        for (int r = 0; r < 4; r++) {
          int g = 4 * m + r;
          int qrow = 4 * hl + r + 8 * m;
          float val = (oacc[wh][g] + part[r]) * linv[g];
          out[((size_t)b * 2048 + qb * 64 + wq * 32 + qrow) * 768 + hh * 64 + wh * 32 + l31] =
              val;
        }
      }
    }
  }
}

// ---------------- launch ----------------
extern "C" void kernel_launch(void* const* d_in, const int* in_sizes, int n_in,
                              void* d_out, int out_size, void* d_ws, size_t ws_size,
                              hipStream_t stream) {
  (void)in_sizes; (void)n_in; (void)out_size; (void)ws_size;
  const float* x  = (const float*)d_in[0];
  const float* Wq = (const float*)d_in[1];
  const float* bq = (const float*)d_in[2];
  const float* Wk = (const float*)d_in[3];
  const float* bk = (const float*)d_in[4];
  const float* Wv = (const float*)d_in[5];
  const float* bv = (const float*)d_in[6];
  const int* mask = (const int*)d_in[7];
  float* out = (float*)d_out;

  char* ws = (char*)d_ws;
  unsigned short* xb = (unsigned short*)(ws);             // 4096x768 bf16   (6291456 B)
  unsigned short* wb = (unsigned short*)(ws + 6291456);   // 3x 768x768 bf16 (3538944 B)
  unsigned short* qw = (unsigned short*)(ws + 9830400);   // Q (B,H,S,W) bf16
  unsigned short* kx = (unsigned short*)(ws + 16121856);  // K' fragment-major bf16
  unsigned short* vx = (unsigned short*)(ws + 22413312);  // V' fragment-major bf16

  cvt_all<<<2400, 256, 0, stream>>>(x, Wq, Wk, Wv, xb, wb);
  proj_gemm<<<dim3(32, 18), 256, 0, stream>>>(xb, wb, bq, bk, bv, qw, kx, vx);
  attn_kernel<<<dim3(32, 24), 256, 0, stream>>>(qw, kx, vx, mask, out);
}

// Round 10
// 90.522 us; speedup vs baseline: 1.0293x; 1.0293x over previous
//
#include <hip/hip_runtime.h>
#include <hip/hip_bf16.h>
#include <stdint.h>

// BERT self-attention fwd: B=2, S=2048, D=768, H=12, W=64. f32 in/out, bf16 MFMA inside.
// Stage 1: cvt x,Wq,Wk,Wv -> bf16.
// Stage 2: QKV projection GEMM. K and V are emitted in FRAGMENT-MAJOR global layouts via an
//   LDS-staged transpose epilogue (scatter ds_write_b16 -> contiguous ds_read_b128 ->
//   coalesced 16B global stores; per head the LDS image is a 16KB contiguous global run):
//   K'[bh][kt][ds][lane][j]: elem = K[key=kt*32+(lane&31)][d=16ds+8(lane>>5)+j]
//   V'[bh][kt][wh][sp][lane][j]: elem = V[key=kt*32+16sp+8(lane>>5)+j][w=wh*32+(lane&31)]
// Stage 3: flash attention, BARRIER-FREE K-loop: each wave owns (32 q) x (wk half of keys),
//   streams K'/V' global->VGPR (K prefetch post-QK, V issued at iter top), swapped QK^T,
//   no-max softmax, in-register P via cvt_pk+permlane32_swap, scalar per-lane row-sum,
//   ballots in a register via readlane. LDS only for the epilogue cross-wk reduce (17KB).

typedef __attribute__((ext_vector_type(8))) short bf16x8;    // 8 bf16 = 4 VGPR (MFMA A/B frag)
typedef __attribute__((ext_vector_type(4))) float f32x4;     // 16x16 MFMA C/D frag
typedef __attribute__((ext_vector_type(16))) float f32x16;   // 32x32 MFMA C/D frag
typedef __attribute__((ext_vector_type(8))) unsigned short u16x8;

#define MFMA16(a, b, c) __builtin_amdgcn_mfma_f32_16x16x32_bf16((a), (b), (c), 0, 0, 0)
#define MFMA32(a, b, c) __builtin_amdgcn_mfma_f32_32x32x16_bf16((a), (b), (c), 0, 0, 0)
#define SWZ(row, colb) ((colb) ^ (((row) & 7) << 4))  // 128B-row swizzle (epilogue only)

union U32x4BF {
  unsigned u[4];
  bf16x8 v;
};

__device__ __forceinline__ void gl_lds16(const void* g, void* l) {
  __builtin_amdgcn_global_load_lds(
      (__attribute__((address_space(1))) void*)const_cast<void*>(g),
      (__attribute__((address_space(3))) void*)l, 16, 0, 0);
}

__device__ __forceinline__ unsigned short f2bf(float x) {  // RNE f32->bf16
  unsigned int v = __float_as_uint(x);
  return (unsigned short)((v + 0x7fffu + ((v >> 16) & 1u)) >> 16);
}

// ---------------- Stage 1: f32 -> bf16 convert ----------------
__global__ __launch_bounds__(256) void cvt_all(
    const float* __restrict__ x, const float* __restrict__ wq,
    const float* __restrict__ wk, const float* __restrict__ wv,
    unsigned short* __restrict__ xb, unsigned short* __restrict__ wb) {
  int i = blockIdx.x * 256 + threadIdx.x;  // group-of-8 index; total 614400
  const float* s;
  unsigned short* d;
  int off;
  if (i < 393216)      { s = x;  d = xb;            off = i; }
  else if (i < 466944) { s = wq; d = wb;            off = i - 393216; }
  else if (i < 540672) { s = wk; d = wb + 589824;   off = i - 466944; }
  else                 { s = wv; d = wb + 1179648;  off = i - 540672; }
  const float4* sp = (const float4*)s + (size_t)off * 2;
  float4 a = sp[0], b2 = sp[1];
  u16x8 o;
  o[0] = f2bf(a.x); o[1] = f2bf(a.y); o[2] = f2bf(a.z); o[3] = f2bf(a.w);
  o[4] = f2bf(b2.x); o[5] = f2bf(b2.y); o[6] = f2bf(b2.z); o[7] = f2bf(b2.w);
  *((u16x8*)d + off) = o;
}

// ---------------- Stage 2: fused QKV projection (BK=32, 3-buf, depth-2) ----------------
__global__ __launch_bounds__(256) void proj_gemm(
    const unsigned short* __restrict__ xb, const unsigned short* __restrict__ wb,
    const float* __restrict__ bq, const float* __restrict__ bk, const float* __restrict__ bv,
    unsigned short* __restrict__ qw, unsigned short* __restrict__ kx,
    unsigned short* __restrict__ vx) {
  __shared__ __align__(16) char psmem[49152];  // 3 bufs x (A 8KB | B 8KB); epilogue: 32KB stage
  const int t = threadIdx.x, lane = t & 63, wave = t >> 6;
  const int lo = lane & 15, hi = lane >> 4;  // hi in 0..3
  const int wr = wave >> 1, wc = wave & 1;   // 2x2 waves, 64x64 each
  const int mbase = blockIdx.x * 128;
  const int wsel = blockIdx.y / 6;
  const int nbase = (blockIdx.y % 6) * 128;
  const char* xc = (const char*)xb;
  const char* wmc = (const char*)(wb + (size_t)wsel * 589824);

  const int pp0 = t * 16, pp1 = t * 16 + 4096;
  const int ar0 = pp0 >> 7, ac0 = (pp0 & 127) ^ ((ar0 & 7) << 4);
  const int am0 = ((ac0 >> 6) << 6) + ar0, ak0 = ac0 & 63;
  const int ar1 = pp1 >> 7, ac1 = (pp1 & 127) ^ ((ar1 & 7) << 4);
  const int am1 = ((ac1 >> 6) << 6) + ar1, ak1 = ac1 & 63;

  const char* xa0 = xc + (size_t)(mbase + am0) * 1536 + ak0;
  const char* xa1 = xc + (size_t)(mbase + am1) * 1536 + ak1;
  const char* wa0 = wmc + (size_t)(nbase + am0) * 1536 + ak0;
  const char* wa1 = wmc + (size_t)(nbase + am1) * 1536 + ak1;

#define PSTAGE(BUF)                              \
  do {                                           \
    char* lb = psmem + (BUF) * 16384;            \
    gl_lds16(xa0, lb + pp0);                     \
    gl_lds16(xa1, lb + pp1);                     \
    gl_lds16(wa0, lb + 8192 + pp0);              \
    gl_lds16(wa1, lb + 8192 + pp1);              \
    xa0 += 64; xa1 += 64; wa0 += 64; wa1 += 64;  \
  } while (0)

  f32x4 acc[4][4];
#pragma unroll
  for (int i = 0; i < 4; i++)
#pragma unroll
    for (int j = 0; j < 4; j++) acc[i][j] = (f32x4){0.f, 0.f, 0.f, 0.f};

  const int axor = (lo & 7) << 4;
  PSTAGE(0);
  PSTAGE(1);
  int cur = 0, sb = 2;
#pragma unroll 1
  for (int it = 0; it < 24; ++it) {
    if (it < 22) {
      PSTAGE(sb);
      asm volatile("s_waitcnt vmcnt(8)" ::: "memory");
    } else if (it == 22) {
      asm volatile("s_waitcnt vmcnt(4)" ::: "memory");
    } else {
      asm volatile("s_waitcnt vmcnt(0)" ::: "memory");
    }
    __builtin_amdgcn_s_barrier();
    const char* lA = psmem + cur * 16384;
    const char* lB = lA + 8192;

    bf16x8 af[4], bf[4];
#pragma unroll
    for (int mf = 0; mf < 4; mf++)
      af[mf] = *(const bf16x8*)(lA + (mf * 16 + lo) * 128 + ((wr * 64 + hi * 16) ^ axor));
#pragma unroll
    for (int nf = 0; nf < 4; nf++)
      bf[nf] = *(const bf16x8*)(lB + (nf * 16 + lo) * 128 + ((wc * 64 + hi * 16) ^ axor));

    __builtin_amdgcn_s_setprio(1);
    if (wsel == 2) {  // V: operand-swapped -> acc holds C^T (rows=n, cols=m)
#pragma unroll
      for (int mf = 0; mf < 4; mf++)
#pragma unroll
        for (int nf = 0; nf < 4; nf++) acc[mf][nf] = MFMA16(bf[nf], af[mf], acc[mf][nf]);
    } else {
#pragma unroll
      for (int mf = 0; mf < 4; mf++)
#pragma unroll
        for (int nf = 0; nf < 4; nf++) acc[mf][nf] = MFMA16(af[mf], bf[nf], acc[mf][nf]);
    }
    __builtin_amdgcn_s_setprio(0);
    __builtin_amdgcn_s_barrier();  // trailing barrier: depth-2 with 3 bufs race-free
    cur = (cur == 2) ? 0 : cur + 1;
    sb = (sb == 2) ? 0 : sb + 1;
  }
#undef PSTAGE

  const float QSCALE = 0.125f * 1.44269504089f;  // fold 1/sqrt(64) * log2(e)
  if (wsel == 0) {
    // Q: direct row-major stores (B,H,S,W)
#pragma unroll
    for (int nf = 0; nf < 4; nf++) {
      int n = nbase + wc * 64 + nf * 16 + lo;
      float bv_ = bq[n];
      int h = n >> 6, wcol = n & 63;
#pragma unroll
      for (int mf = 0; mf < 4; mf++) {
#pragma unroll
        for (int r = 0; r < 4; r++) {
          int m = mbase + wr * 64 + mf * 16 + hi * 4 + r;
          int b_ = m >> 11, s = m & 2047;
          float val = acc[mf][nf][r] + bv_;
          qw[(((size_t)b_ * 12 + h) * 2048 + s) * 64 + wcol] = f2bf(val * QSCALE);
        }
      }
    }
  } else {
    // K'/V': LDS-staged transpose epilogue. Stage 32KB fragment-major image in psmem:
    //   [h_local(2)][ktl(4)][rest 4KB] -- per head a 16KB contiguous run of the global array.
    __syncthreads();  // all K-loop LDS reads done (trailing barrier) -- belt & braces
    if (wsel == 1) {
      // K' elem (key s, d): off = h*16384 + ktl*4096 + (d>>4)*1024 + ((d>>3)&1)*512
      //                         + (s&31)*16 + (d&7)*2
#pragma unroll
      for (int nf = 0; nf < 4; nf++) {
        int n = nbase + wc * 64 + nf * 16 + lo;
        float bv_ = bk[n];
        int d = n & 63;
        int basen = ((n >> 6) & 1) * 16384 + (d >> 4) * 1024 + ((d >> 3) & 1) * 512 + (d & 7) * 2;
#pragma unroll
        for (int mf = 0; mf < 4; mf++) {
#pragma unroll
          for (int r = 0; r < 4; r++) {
            int ml = wr * 64 + mf * 16 + hi * 4 + r;  // m - mbase in [0,128)
            *(unsigned short*)(psmem + basen + (ml >> 5) * 4096 + (ml & 31) * 16) =
                f2bf(acc[mf][nf][r] + bv_);
          }
        }
      }
    } else {
      // V' elem (key s, w): off = h*16384 + ktl*4096 + ((w>>5)&1)*2048 + ((s>>4)&1)*1024
      //                         + ((s>>3)&1)*512 + (w&31)*16 + (s&7)*2   (acc holds C^T)
#pragma unroll
      for (int mf = 0; mf < 4; mf++) {
        int ml = wr * 64 + mf * 16 + lo;  // s-local
        int basem = (ml >> 5) * 4096 + ((ml >> 4) & 1) * 1024 + ((ml >> 3) & 1) * 512 + (ml & 7) * 2;
#pragma unroll
        for (int nf = 0; nf < 4; nf++) {
#pragma unroll
          for (int r = 0; r < 4; r++) {
            int n = nbase + wc * 64 + nf * 16 + hi * 4 + r;
            int w = n & 63;
            int off = ((n >> 6) & 1) * 16384 + basem + ((w >> 5) & 1) * 2048 + (w & 31) * 16;
            *(unsigned short*)(psmem + off) = f2bf(acc[mf][nf][r] + bv[n]);
          }
        }
      }
    }
    __syncthreads();
    // coalesced copy-out: per head, LDS 16KB run -> global 16KB contiguous run
    const int bblk = mbase >> 11;
    const int h0 = nbase >> 6;                 // first head (nbase is 128-aligned)
    const int ktb = (mbase & 2047) >> 5;       // kt base of this m-tile
    char* dst = (char*)((wsel == 1) ? kx : vx);
    size_t gb = ((size_t)(bblk * 12 + h0) * 131072 + (size_t)ktb * 2048) * 2;
#pragma unroll
    for (int c = 0; c < 4; c++) {
      int lb = c * 4096 + t * 16;
      *(u16x8*)(dst + gb + lb) = *(const u16x8*)(psmem + lb);
    }
    gb += (size_t)131072 * 2;  // head h0+1
#pragma unroll
    for (int c = 0; c < 4; c++) {
      int lb = c * 4096 + t * 16;
      *(u16x8*)(dst + gb + lb) = *(const u16x8*)(psmem + 16384 + lb);
    }
  }
}

// ---------------- Stage 3: flash attention (barrier-free K-loop) ----------------
// grid (32, 24), block 256 = 4 waves (wq q-half x wk key-half). Each wave: 32 iters over
// its 32-key tiles (kt = wk*32 + it), streaming K'/V' fragments global->VGPR coalesced.
// Per iter: issue V(it) -> QK(it) from prefetched K regs -> prefetch K(it+1) -> softmax
// (exp2, log2e folded into Q) -> cvt_pk+permlane -> PV. No __syncthreads in the loop.
__global__ __launch_bounds__(256) void attn_kernel(
    const unsigned short* __restrict__ qw, const unsigned short* __restrict__ kx,
    const unsigned short* __restrict__ vx, const int* __restrict__ mask,
    float* __restrict__ out) {
  // [0,16384) epilogue O-staging (2 wq x 8KB) | [16384,16640) ballot bytes |
  // [16640,17152) lsum f32[128]: ((wq*32+q)*2 + wk)
  __shared__ __align__(16) char smem[17152];
  const int t = threadIdx.x, lane = t & 63, wave = t >> 6;
  const int wq = wave >> 1, wk = wave & 1;
  const int l31 = lane & 31, hl = lane >> 5;
  const int qb = blockIdx.x, bh = blockIdx.y;
  const int b = bh / 12, hh = bh - b * 12;

  // bit-pack mask: thread t packs keys [t*8, t*8+8) -> ballot bytes
  {
    const int* mb = mask + (size_t)b * 2048 + t * 8;
    int4 a0 = *(const int4*)mb;
    int4 a1 = *(const int4*)(mb + 4);
    unsigned by = (unsigned)(a0.x != 0) | ((unsigned)(a0.y != 0) << 1) |
                  ((unsigned)(a0.z != 0) << 2) | ((unsigned)(a0.w != 0) << 3) |
                  ((unsigned)(a1.x != 0) << 4) | ((unsigned)(a1.y != 0) << 5) |
                  ((unsigned)(a1.z != 0) << 6) | ((unsigned)(a1.w != 0) << 7);
    smem[16384 + t] = (char)by;
  }
  __syncthreads();
  // lane i holds the 32-key ballot of this wave's tile (i&31)
  const unsigned balv = *(const unsigned*)(smem + 16384 + (wk * 32 + l31) * 4);

  // Q B-frags: lane holds Q[q = l31 of wq-half][d = 16s + 8hl + j]
  bf16x8 qv[4];
  {
    int qrow = qb * 64 + wq * 32 + l31;
    const char* qp = (const char*)qw + ((size_t)bh * 2048 + qrow) * 128 + hl * 16;
#pragma unroll
    for (int s = 0; s < 4; s++) qv[s] = *(const bf16x8*)(qp + s * 32);
  }

  // fragment stream pointers (coalesced: lane*16 within 1KB chunks)
  const char* kp = (const char*)kx + (size_t)bh * 262144 + (size_t)wk * 131072 + lane * 16;
  const char* vp = (const char*)vx + (size_t)bh * 262144 + (size_t)wk * 131072 + lane * 16;

  f32x16 oacc[2];
#pragma unroll
  for (int wh = 0; wh < 2; wh++)
#pragma unroll
    for (int g = 0; g < 16; g++) oacc[wh][g] = 0.f;
  float lacc = 0.f;  // per-lane row-sum for q = l31 (this wave's hl/wk slice)

  // prologue: K(0) fragments
  bf16x8 ka0 = *(const bf16x8*)(kp);
  bf16x8 ka1 = *(const bf16x8*)(kp + 1024);
  bf16x8 ka2 = *(const bf16x8*)(kp + 2048);
  bf16x8 ka3 = *(const bf16x8*)(kp + 3072);
  kp += 4096;

#pragma unroll 2
  for (int it = 0; it < 32; ++it) {
    // issue V(it) early (consumed after softmax, ~300+ cyc later)
    bf16x8 v00 = *(const bf16x8*)(vp);          // wh0 sp0
    bf16x8 v01 = *(const bf16x8*)(vp + 1024);   // wh0 sp1
    bf16x8 v10 = *(const bf16x8*)(vp + 2048);   // wh1 sp0
    bf16x8 v11 = *(const bf16x8*)(vp + 3072);   // wh1 sp1
    vp += 4096;

    // QK^T swapped: sc[g] = S^T[key-in-tile = (g&3)+8(g>>2)+4hl][q = l31]
    f32x16 sc;
#pragma unroll
    for (int g = 0; g < 16; g++) sc[g] = 0.f;
    __builtin_amdgcn_s_setprio(1);
    sc = MFMA32(ka0, qv[0], sc);
    sc = MFMA32(ka1, qv[1], sc);
    sc = MFMA32(ka2, qv[2], sc);
    sc = MFMA32(ka3, qv[3], sc);
    __builtin_amdgcn_s_setprio(0);

    // prefetch K(it+1); at it=31 this harmlessly reads the adjacent V' array
    ka0 = *(const bf16x8*)(kp);
    ka1 = *(const bf16x8*)(kp + 1024);
    ka2 = *(const bf16x8*)(kp + 2048);
    ka3 = *(const bf16x8*)(kp + 3072);
    kp += 4096;

    // mask (uniform skip when all-ones)
    unsigned bal = __builtin_amdgcn_readlane(balv, it);
    if (bal != 0xFFFFFFFFu) {
#pragma unroll
      for (int g = 0; g < 16; g++) {
        int key = (g & 3) + 8 * (g >> 2) + 4 * hl;
        if (!((bal >> key) & 1)) sc[g] = -30000.f;  // exp2 -> 0
      }
    }

    // P = exp2(sc) in place; per-lane row-sum; pack to bf16 A-frags
#pragma unroll
    for (int g = 0; g < 16; g++) {
      float e_;
      asm("v_exp_f32 %0, %1" : "=v"(e_) : "v"(sc[g]));
      sc[g] = e_;
    }
    lacc += (((sc[0] + sc[1]) + (sc[2] + sc[3])) + ((sc[4] + sc[5]) + (sc[6] + sc[7]))) +
            (((sc[8] + sc[9]) + (sc[10] + sc[11])) + ((sc[12] + sc[13]) + (sc[14] + sc[15])));
    unsigned pk[4][2];
#pragma unroll
    for (int m = 0; m < 4; m++) {
      asm("v_cvt_pk_bf16_f32 %0, %1, %2" : "=v"(pk[m][0]) : "v"(sc[4 * m]), "v"(sc[4 * m + 1]));
      asm("v_cvt_pk_bf16_f32 %0, %1, %2" : "=v"(pk[m][1]) : "v"(sc[4 * m + 2]), "v"(sc[4 * m + 3]));
    }
    U32x4BF apv[2];  // A[q=l31][k_local = 16sp + 8hl + j]
#pragma unroll
    for (int sp = 0; sp < 2; sp++)
#pragma unroll
      for (int cp = 0; cp < 2; cp++) {
        unsigned xx = pk[2 * sp][cp], yy = pk[2 * sp + 1][cp];
        asm("v_permlane32_swap_b32 %0, %1" : "+v"(xx), "+v"(yy));
        apv[sp].u[cp] = xx;
        apv[sp].u[2 + cp] = yy;
      }

    // PV: oacc[wh] += P(32q x 32k) @ V(32k x 32w)
    __builtin_amdgcn_s_setprio(1);
    oacc[0] = MFMA32(apv[0].v, v00, oacc[0]);
    oacc[0] = MFMA32(apv[1].v, v01, oacc[0]);
    oacc[1] = MFMA32(apv[0].v, v10, oacc[1]);
    oacc[1] = MFMA32(apv[1].v, v11, oacc[1]);
    __builtin_amdgcn_s_setprio(0);
  }

  // ---- epilogue: cross-wk reduce of O and l, then out = O / l ----
  lacc += __shfl_xor(lacc, 32);  // combine hl halves; all lanes hold sum for q=l31 (wk half)
  if (lane < 32)
    *(float*)(smem + 16640 + (((wq * 32 + l31) << 1) + wk) * 4) = lacc;
  if (wk == 1) {  // partial O as [w][q] f32 into [0,16384)
#pragma unroll
    for (int wh = 0; wh < 2; wh++) {
      int vrow = wh * 32 + l31;
#pragma unroll
      for (int m = 0; m < 4; m++) {
        f32x4 part = (f32x4){oacc[wh][4 * m], oacc[wh][4 * m + 1],
                             oacc[wh][4 * m + 2], oacc[wh][4 * m + 3]};
        *(f32x4*)(smem + wq * 8192 + vrow * 128 + SWZ(vrow, hl * 16 + m * 32)) = part;
      }
    }
  }
  __syncthreads();
  if (wk == 0) {
    float linv[16];
#pragma unroll
    for (int g = 0; g < 16; g++) {
      int qrow = 4 * hl + (g & 3) + 8 * (g >> 2);
      float2 lp = *(const float2*)(smem + 16640 + ((wq * 32 + qrow) << 3));
      linv[g] = __builtin_amdgcn_rcpf(lp.x + lp.y);
    }
#pragma unroll
    for (int wh = 0; wh < 2; wh++) {
      int vrow = wh * 32 + l31;
#pragma unroll
      for (int m = 0; m < 4; m++) {
        f32x4 part = *(const f32x4*)(smem + wq * 8192 + vrow * 128 + SWZ(vrow, hl * 16 + m * 32));
#pragma unroll
        for (int r = 0; r < 4; r++) {
          int g = 4 * m + r;
          int qrow = 4 * hl + r + 8 * m;
          float val = (oacc[wh][g] + part[r]) * linv[g];
          out[((size_t)b * 2048 + qb * 64 + wq * 32 + qrow) * 768 + hh * 64 + wh * 32 + l31] =
              val;
        }
      }
    }
  }
}

// ---------------- launch ----------------
extern "C" void kernel_launch(void* const* d_in, const int* in_sizes, int n_in,
                              void* d_out, int out_size, void* d_ws, size_t ws_size,
                              hipStream_t stream) {
  (void)in_sizes; (void)n_in; (void)out_size; (void)ws_size;
  const float* x  = (const float*)d_in[0];
  const float* Wq = (const float*)d_in[1];
  const float* bq = (const float*)d_in[2];
  const float* Wk = (const float*)d_in[3];
  const float* bk = (const float*)d_in[4];
  const float* Wv = (const float*)d_in[5];
  const float* bv = (const float*)d_in[6];
  const int* mask = (const int*)d_in[7];
  float* out = (float*)d_out;

  char* ws = (char*)d_ws;
  unsigned short* xb = (unsigned short*)(ws);             // 4096x768 bf16   (6291456 B)
  unsigned short* wb = (unsigned short*)(ws + 6291456);   // 3x 768x768 bf16 (3538944 B)
  unsigned short* qw = (unsigned short*)(ws + 9830400);   // Q (B,H,S,W) bf16
  unsigned short* kx = (unsigned short*)(ws + 16121856);  // K' fragment-major bf16
  unsigned short* vx = (unsigned short*)(ws + 22413312);  // V' fragment-major bf16

  cvt_all<<<2400, 256, 0, stream>>>(x, Wq, Wk, Wv, xb, wb);
  proj_gemm<<<dim3(32, 18), 256, 0, stream>>>(xb, wb, bq, bk, bv, qw, kx, vx);
  attn_kernel<<<dim3(32, 24), 256, 0, stream>>>(qw, kx, vx, mask, out);
}

// Round 11
// 85.915 us; speedup vs baseline: 1.0845x; 1.0536x over previous
//
#include <hip/hip_runtime.h>
#include <hip/hip_bf16.h>
#include <stdint.h>

// BERT self-attention fwd: B=2, S=2048, D=768, H=12, W=64. f32 in/out, bf16 MFMA inside.
// Stage 1: cvt x,Wq,Wk,Wv -> bf16.
// Stage 2: QKV projection GEMM (R6-proven structure): Q/K row-major (B,H,S,W), V^T (B,H,W,S).
// Stage 2.5: relayout_kv: K,V^T -> fragment-major K'/V' via 32KB LDS image, coalesced both
//   sides. kx overwrites xb; vx overwrites kw (each block rewrites only bytes it read).
//   K'[bh][kt][ds][lane][j]: elem = K[key=kt*32+(lane&31)][d=16ds+8(lane>>5)+j]
//   V'[bh][kt][wh][sp][lane][j]: elem = V[key=kt*32+16sp+8(lane>>5)+j][w=wh*32+(lane&31)]
// Stage 3: flash attention, BARRIER-FREE K-loop (R10): waves stream K'/V' global->VGPR
//   coalesced, swapped QK^T, no-max softmax, cvt_pk+permlane32_swap in-register P,
//   per-lane row-sum, readlane ballots. LDS only for epilogue cross-wk reduce.

typedef __attribute__((ext_vector_type(8))) short bf16x8;    // 8 bf16 = 4 VGPR (MFMA A/B frag)
typedef __attribute__((ext_vector_type(4))) float f32x4;     // 16x16 MFMA C/D frag
typedef __attribute__((ext_vector_type(16))) float f32x16;   // 32x32 MFMA C/D frag
typedef __attribute__((ext_vector_type(8))) unsigned short u16x8;

#define MFMA16(a, b, c) __builtin_amdgcn_mfma_f32_16x16x32_bf16((a), (b), (c), 0, 0, 0)
#define MFMA32(a, b, c) __builtin_amdgcn_mfma_f32_32x32x16_bf16((a), (b), (c), 0, 0, 0)
#define SWZ(row, colb) ((colb) ^ (((row) & 7) << 4))  // 128B-row swizzle

union U32x4BF {
  unsigned u[4];
  bf16x8 v;
};

__device__ __forceinline__ void gl_lds16(const void* g, void* l) {
  __builtin_amdgcn_global_load_lds(
      (__attribute__((address_space(1))) void*)const_cast<void*>(g),
      (__attribute__((address_space(3))) void*)l, 16, 0, 0);
}

__device__ __forceinline__ unsigned short f2bf(float x) {  // RNE f32->bf16
  unsigned int v = __float_as_uint(x);
  return (unsigned short)((v + 0x7fffu + ((v >> 16) & 1u)) >> 16);
}

// ---------------- Stage 1: f32 -> bf16 convert ----------------
__global__ __launch_bounds__(256) void cvt_all(
    const float* __restrict__ x, const float* __restrict__ wq,
    const float* __restrict__ wk, const float* __restrict__ wv,
    unsigned short* __restrict__ xb, unsigned short* __restrict__ wb) {
  int i = blockIdx.x * 256 + threadIdx.x;  // group-of-8 index; total 614400
  const float* s;
  unsigned short* d;
  int off;
  if (i < 393216)      { s = x;  d = xb;            off = i; }
  else if (i < 466944) { s = wq; d = wb;            off = i - 393216; }
  else if (i < 540672) { s = wk; d = wb + 589824;   off = i - 466944; }
  else                 { s = wv; d = wb + 1179648;  off = i - 540672; }
  const float4* sp = (const float4*)s + (size_t)off * 2;
  float4 a = sp[0], b2 = sp[1];
  u16x8 o;
  o[0] = f2bf(a.x); o[1] = f2bf(a.y); o[2] = f2bf(a.z); o[3] = f2bf(a.w);
  o[4] = f2bf(b2.x); o[5] = f2bf(b2.y); o[6] = f2bf(b2.z); o[7] = f2bf(b2.w);
  *((u16x8*)d + off) = o;
}

// ---------------- Stage 2: fused QKV projection (exact R6 structure) ----------------
__global__ __launch_bounds__(256) void proj_gemm(
    const unsigned short* __restrict__ xb, const unsigned short* __restrict__ wb,
    const float* __restrict__ bq, const float* __restrict__ bk, const float* __restrict__ bv,
    unsigned short* __restrict__ qw, unsigned short* __restrict__ kw,
    unsigned short* __restrict__ vw) {
  __shared__ __align__(16) char psmem[49152];  // 3 bufs x (A 8KB | B 8KB)
  const int t = threadIdx.x, lane = t & 63, wave = t >> 6;
  const int lo = lane & 15, hi = lane >> 4;  // hi in 0..3
  const int wr = wave >> 1, wc = wave & 1;   // 2x2 waves, 64x64 each
  const int mbase = blockIdx.x * 128;
  const int wsel = blockIdx.y / 6;
  const int nbase = (blockIdx.y % 6) * 128;
  const char* xc = (const char*)xb;
  const char* wmc = (const char*)(wb + (size_t)wsel * 589824);

  const int pp0 = t * 16, pp1 = t * 16 + 4096;
  const int ar0 = pp0 >> 7, ac0 = (pp0 & 127) ^ ((ar0 & 7) << 4);
  const int am0 = ((ac0 >> 6) << 6) + ar0, ak0 = ac0 & 63;
  const int ar1 = pp1 >> 7, ac1 = (pp1 & 127) ^ ((ar1 & 7) << 4);
  const int am1 = ((ac1 >> 6) << 6) + ar1, ak1 = ac1 & 63;

  const char* xa0 = xc + (size_t)(mbase + am0) * 1536 + ak0;
  const char* xa1 = xc + (size_t)(mbase + am1) * 1536 + ak1;
  const char* wa0 = wmc + (size_t)(nbase + am0) * 1536 + ak0;
  const char* wa1 = wmc + (size_t)(nbase + am1) * 1536 + ak1;

#define PSTAGE(BUF)                              \
  do {                                           \
    char* lb = psmem + (BUF) * 16384;            \
    gl_lds16(xa0, lb + pp0);                     \
    gl_lds16(xa1, lb + pp1);                     \
    gl_lds16(wa0, lb + 8192 + pp0);              \
    gl_lds16(wa1, lb + 8192 + pp1);              \
    xa0 += 64; xa1 += 64; wa0 += 64; wa1 += 64;  \
  } while (0)

  f32x4 acc[4][4];
#pragma unroll
  for (int i = 0; i < 4; i++)
#pragma unroll
    for (int j = 0; j < 4; j++) acc[i][j] = (f32x4){0.f, 0.f, 0.f, 0.f};

  const int axor = (lo & 7) << 4;
  PSTAGE(0);
  PSTAGE(1);
  int cur = 0, sb = 2;
#pragma unroll 1
  for (int it = 0; it < 24; ++it) {
    if (it < 22) {
      PSTAGE(sb);
      asm volatile("s_waitcnt vmcnt(8)" ::: "memory");
    } else if (it == 22) {
      asm volatile("s_waitcnt vmcnt(4)" ::: "memory");
    } else {
      asm volatile("s_waitcnt vmcnt(0)" ::: "memory");
    }
    __builtin_amdgcn_s_barrier();
    const char* lA = psmem + cur * 16384;
    const char* lB = lA + 8192;

    bf16x8 af[4], bf[4];
#pragma unroll
    for (int mf = 0; mf < 4; mf++)
      af[mf] = *(const bf16x8*)(lA + (mf * 16 + lo) * 128 + ((wr * 64 + hi * 16) ^ axor));
#pragma unroll
    for (int nf = 0; nf < 4; nf++)
      bf[nf] = *(const bf16x8*)(lB + (nf * 16 + lo) * 128 + ((wc * 64 + hi * 16) ^ axor));

    __builtin_amdgcn_s_setprio(1);
    if (wsel == 2) {  // V: operand-swapped -> acc holds C^T (rows=n, cols=m)
#pragma unroll
      for (int mf = 0; mf < 4; mf++)
#pragma unroll
        for (int nf = 0; nf < 4; nf++) acc[mf][nf] = MFMA16(bf[nf], af[mf], acc[mf][nf]);
    } else {
#pragma unroll
      for (int mf = 0; mf < 4; mf++)
#pragma unroll
        for (int nf = 0; nf < 4; nf++) acc[mf][nf] = MFMA16(af[mf], bf[nf], acc[mf][nf]);
    }
    __builtin_amdgcn_s_setprio(0);
    __builtin_amdgcn_s_barrier();  // trailing barrier: depth-2 with 3 bufs race-free
    cur = (cur == 2) ? 0 : cur + 1;
    sb = (sb == 2) ? 0 : sb + 1;
  }
#undef PSTAGE

  const float QSCALE = 0.125f * 1.44269504089f;  // fold 1/sqrt(64) * log2(e)
  if (wsel == 2) {
#pragma unroll
    for (int nf = 0; nf < 4; nf++) {
#pragma unroll
      for (int mf = 0; mf < 4; mf++) {
#pragma unroll
        for (int r = 0; r < 4; r++) {
          int n = nbase + wc * 64 + nf * 16 + hi * 4 + r;
          int m = mbase + wr * 64 + mf * 16 + lo;
          int b_ = m >> 11, s = m & 2047;
          int h = n >> 6, wcol = n & 63;
          float val = acc[mf][nf][r] + bv[n];
          vw[(((size_t)b_ * 12 + h) * 64 + wcol) * 2048 + s] = f2bf(val);
        }
      }
    }
  } else {
    const float* bias = (wsel == 0) ? bq : bk;
#pragma unroll
    for (int nf = 0; nf < 4; nf++) {
      int n = nbase + wc * 64 + nf * 16 + lo;
      float bv_ = bias[n];
      int h = n >> 6, wcol = n & 63;
#pragma unroll
      for (int mf = 0; mf < 4; mf++) {
#pragma unroll
        for (int r = 0; r < 4; r++) {
          int m = mbase + wr * 64 + mf * 16 + hi * 4 + r;
          int b_ = m >> 11, s = m & 2047;
          float val = acc[mf][nf][r] + bv_;
          size_t bhh = (size_t)b_ * 12 + h;
          if (wsel == 0)
            qw[(bhh * 2048 + s) * 64 + wcol] = f2bf(val * QSCALE);
          else
            kw[(bhh * 2048 + s) * 64 + wcol] = f2bf(val);
        }
      }
    }
  }
}

// ---------------- Stage 2.5: relayout K,V^T -> fragment-major K',V' ----------------
// grid (16, 24), block 256. Block (ktq, bh) handles kts [ktq*4, +4): 16KB of K + 16KB of V.
// vx aliases kw: each block overwrites exactly the kw bytes it alone read (post-barrier).
__global__ __launch_bounds__(256) void relayout_kv(
    const unsigned short* kw, const unsigned short* __restrict__ vwT,
    unsigned short* __restrict__ kx, unsigned short* vx) {
  __shared__ __align__(16) char rsm[32768];  // [0,16K) K' image | [16K,32K) V' image
  const int t = threadIdx.x;
  const int ktq = blockIdx.x, bh = blockIdx.y;
  const size_t bhb = (size_t)bh * 262144;  // per-bh byte stride in all four arrays
  const int kt0 = ktq * 4;

  // K stage: thread reads K[key][d0..d0+8) (16B row-major chunk), writes 16B frag-major LDS
  {
    const int key = t >> 3;      // key-in-tile 0..31
    const int d0 = (t & 7) * 8;  // 0..56
    const char* ksrc = (const char*)kw + bhb + (size_t)kt0 * 4096 + key * 128 + d0 * 2;
    char* kldst = rsm + (d0 >> 4) * 1024 + ((d0 >> 3) & 1) * 512 + key * 16;
#pragma unroll
    for (int c = 0; c < 4; c++)
      *(u16x8*)(kldst + c * 4096) = *(const u16x8*)(ksrc + c * 4096);
  }
  // V stage: thread reads V^T[w][s0..s0+8) (16B s-contiguous), writes 16B frag-major LDS
  {
    const int w = t >> 2;         // 0..63
    const int sl0 = (t & 3) * 8;  // s-in-tile base 0,8,16,24
    const char* vsrc = (const char*)vwT + bhb + (size_t)w * 4096 + (kt0 * 32 + sl0) * 2;
    char* vldst = rsm + 16384 + (w >> 5) * 2048 + ((sl0 >> 4) & 1) * 1024 +
                  ((sl0 >> 3) & 1) * 512 + (w & 31) * 16;
#pragma unroll
    for (int c = 0; c < 4; c++)
      *(u16x8*)(vldst + c * 4096) = *(const u16x8*)(vsrc + c * 64);
  }
  __syncthreads();  // LDS images complete; all this block's kw reads drained

  // copy-out: both images are contiguous 16KB runs of the global arrays
  char* kdst = (char*)kx + bhb + (size_t)ktq * 16384;
  char* vdst = (char*)vx + bhb + (size_t)ktq * 16384;
#pragma unroll
  for (int c = 0; c < 4; c++) {
    int lb = c * 4096 + t * 16;
    *(u16x8*)(kdst + lb) = *(const u16x8*)(rsm + lb);
    *(u16x8*)(vdst + lb) = *(const u16x8*)(rsm + 16384 + lb);
  }
}

// ---------------- Stage 3: flash attention (barrier-free K-loop, R10) ----------------
__global__ __launch_bounds__(256) void attn_kernel(
    const unsigned short* __restrict__ qw, const unsigned short* __restrict__ kx,
    const unsigned short* __restrict__ vx, const int* __restrict__ mask,
    float* __restrict__ out) {
  // [0,16384) epilogue O-staging (2 wq x 8KB) | [16384,16640) ballot bytes |
  // [16640,17152) lsum f32[128]: ((wq*32+q)*2 + wk)
  __shared__ __align__(16) char smem[17152];
  const int t = threadIdx.x, lane = t & 63, wave = t >> 6;
  const int wq = wave >> 1, wk = wave & 1;
  const int l31 = lane & 31, hl = lane >> 5;
  const int qb = blockIdx.x, bh = blockIdx.y;
  const int b = bh / 12, hh = bh - b * 12;

  // bit-pack mask: thread t packs keys [t*8, t*8+8) -> ballot bytes
  {
    const int* mb = mask + (size_t)b * 2048 + t * 8;
    int4 a0 = *(const int4*)mb;
    int4 a1 = *(const int4*)(mb + 4);
    unsigned by = (unsigned)(a0.x != 0) | ((unsigned)(a0.y != 0) << 1) |
                  ((unsigned)(a0.z != 0) << 2) | ((unsigned)(a0.w != 0) << 3) |
                  ((unsigned)(a1.x != 0) << 4) | ((unsigned)(a1.y != 0) << 5) |
                  ((unsigned)(a1.z != 0) << 6) | ((unsigned)(a1.w != 0) << 7);
    smem[16384 + t] = (char)by;
  }
  __syncthreads();
  // lane i holds the 32-key ballot of this wave's tile (i&31)
  const unsigned balv = *(const unsigned*)(smem + 16384 + (wk * 32 + l31) * 4);

  // Q B-frags: lane holds Q[q = l31 of wq-half][d = 16s + 8hl + j]
  bf16x8 qv[4];
  {
    int qrow = qb * 64 + wq * 32 + l31;
    const char* qp = (const char*)qw + ((size_t)bh * 2048 + qrow) * 128 + hl * 16;
#pragma unroll
    for (int s = 0; s < 4; s++) qv[s] = *(const bf16x8*)(qp + s * 32);
  }

  // fragment stream pointers (coalesced: lane*16 within 1KB chunks)
  const char* kp = (const char*)kx + (size_t)bh * 262144 + (size_t)wk * 131072 + lane * 16;
  const char* vp = (const char*)vx + (size_t)bh * 262144 + (size_t)wk * 131072 + lane * 16;

  f32x16 oacc[2];
#pragma unroll
  for (int wh = 0; wh < 2; wh++)
#pragma unroll
    for (int g = 0; g < 16; g++) oacc[wh][g] = 0.f;
  float lacc = 0.f;  // per-lane row-sum for q = l31 (this wave's hl/wk slice)

  // prologue: K(0) fragments
  bf16x8 ka0 = *(const bf16x8*)(kp);
  bf16x8 ka1 = *(const bf16x8*)(kp + 1024);
  bf16x8 ka2 = *(const bf16x8*)(kp + 2048);
  bf16x8 ka3 = *(const bf16x8*)(kp + 3072);
  kp += 4096;

#pragma unroll 2
  for (int it = 0; it < 32; ++it) {
    // issue V(it) early (consumed after softmax, ~300+ cyc later)
    bf16x8 v00 = *(const bf16x8*)(vp);          // wh0 sp0
    bf16x8 v01 = *(const bf16x8*)(vp + 1024);   // wh0 sp1
    bf16x8 v10 = *(const bf16x8*)(vp + 2048);   // wh1 sp0
    bf16x8 v11 = *(const bf16x8*)(vp + 3072);   // wh1 sp1
    vp += 4096;

    // QK^T swapped: sc[g] = S^T[key-in-tile = (g&3)+8(g>>2)+4hl][q = l31]
    f32x16 sc;
#pragma unroll
    for (int g = 0; g < 16; g++) sc[g] = 0.f;
    __builtin_amdgcn_s_setprio(1);
    sc = MFMA32(ka0, qv[0], sc);
    sc = MFMA32(ka1, qv[1], sc);
    sc = MFMA32(ka2, qv[2], sc);
    sc = MFMA32(ka3, qv[3], sc);
    __builtin_amdgcn_s_setprio(0);

    // prefetch K(it+1); at it=31 this harmlessly reads adjacent valid memory
    ka0 = *(const bf16x8*)(kp);
    ka1 = *(const bf16x8*)(kp + 1024);
    ka2 = *(const bf16x8*)(kp + 2048);
    ka3 = *(const bf16x8*)(kp + 3072);
    kp += 4096;

    // mask (uniform skip when all-ones)
    unsigned bal = __builtin_amdgcn_readlane(balv, it);
    if (bal != 0xFFFFFFFFu) {
#pragma unroll
      for (int g = 0; g < 16; g++) {
        int key = (g & 3) + 8 * (g >> 2) + 4 * hl;
        if (!((bal >> key) & 1)) sc[g] = -30000.f;  // exp2 -> 0
      }
    }

    // P = exp2(sc) in place; per-lane row-sum; pack to bf16 A-frags
#pragma unroll
    for (int g = 0; g < 16; g++) {
      float e_;
      asm("v_exp_f32 %0, %1" : "=v"(e_) : "v"(sc[g]));
      sc[g] = e_;
    }
    lacc += (((sc[0] + sc[1]) + (sc[2] + sc[3])) + ((sc[4] + sc[5]) + (sc[6] + sc[7]))) +
            (((sc[8] + sc[9]) + (sc[10] + sc[11])) + ((sc[12] + sc[13]) + (sc[14] + sc[15])));
    unsigned pk[4][2];
#pragma unroll
    for (int m = 0; m < 4; m++) {
      asm("v_cvt_pk_bf16_f32 %0, %1, %2" : "=v"(pk[m][0]) : "v"(sc[4 * m]), "v"(sc[4 * m + 1]));
      asm("v_cvt_pk_bf16_f32 %0, %1, %2" : "=v"(pk[m][1]) : "v"(sc[4 * m + 2]), "v"(sc[4 * m + 3]));
    }
    U32x4BF apv[2];  // A[q=l31][k_local = 16sp + 8hl + j]
#pragma unroll
    for (int sp = 0; sp < 2; sp++)
#pragma unroll
      for (int cp = 0; cp < 2; cp++) {
        unsigned xx = pk[2 * sp][cp], yy = pk[2 * sp + 1][cp];
        asm("v_permlane32_swap_b32 %0, %1" : "+v"(xx), "+v"(yy));
        apv[sp].u[cp] = xx;
        apv[sp].u[2 + cp] = yy;
      }

    // PV: oacc[wh] += P(32q x 32k) @ V(32k x 32w)
    __builtin_amdgcn_s_setprio(1);
    oacc[0] = MFMA32(apv[0].v, v00, oacc[0]);
    oacc[0] = MFMA32(apv[1].v, v01, oacc[0]);
    oacc[1] = MFMA32(apv[0].v, v10, oacc[1]);
    oacc[1] = MFMA32(apv[1].v, v11, oacc[1]);
    __builtin_amdgcn_s_setprio(0);
  }

  // ---- epilogue: cross-wk reduce of O and l, then out = O / l ----
  lacc += __shfl_xor(lacc, 32);  // combine hl halves; all lanes hold sum for q=l31 (wk half)
  if (lane < 32)
    *(float*)(smem + 16640 + (((wq * 32 + l31) << 1) + wk) * 4) = lacc;
  if (wk == 1) {  // partial O as [w][q] f32 into [0,16384)
#pragma unroll
    for (int wh = 0; wh < 2; wh++) {
      int vrow = wh * 32 + l31;
#pragma unroll
      for (int m = 0; m < 4; m++) {
        f32x4 part = (f32x4){oacc[wh][4 * m], oacc[wh][4 * m + 1],
                             oacc[wh][4 * m + 2], oacc[wh][4 * m + 3]};
        *(f32x4*)(smem + wq * 8192 + vrow * 128 + SWZ(vrow, hl * 16 + m * 32)) = part;
      }
    }
  }
  __syncthreads();
  if (wk == 0) {
    float linv[16];
#pragma unroll
    for (int g = 0; g < 16; g++) {
      int qrow = 4 * hl + (g & 3) + 8 * (g >> 2);
      float2 lp = *(const float2*)(smem + 16640 + ((wq * 32 + qrow) << 3));
      linv[g] = __builtin_amdgcn_rcpf(lp.x + lp.y);
    }
#pragma unroll
    for (int wh = 0; wh < 2; wh++) {
      int vrow = wh * 32 + l31;
#pragma unroll
      for (int m = 0; m < 4; m++) {
        f32x4 part = *(const f32x4*)(smem + wq * 8192 + vrow * 128 + SWZ(vrow, hl * 16 + m * 32));
#pragma unroll
        for (int r = 0; r < 4; r++) {
          int g = 4 * m + r;
          int qrow = 4 * hl + r + 8 * m;
          float val = (oacc[wh][g] + part[r]) * linv[g];
          out[((size_t)b * 2048 + qb * 64 + wq * 32 + qrow) * 768 + hh * 64 + wh * 32 + l31] =
              val;
        }
      }
    }
  }
}

// ---------------- launch ----------------
extern "C" void kernel_launch(void* const* d_in, const int* in_sizes, int n_in,
                              void* d_out, int out_size, void* d_ws, size_t ws_size,
                              hipStream_t stream) {
  (void)in_sizes; (void)n_in; (void)out_size; (void)ws_size;
  const float* x  = (const float*)d_in[0];
  const float* Wq = (const float*)d_in[1];
  const float* bq = (const float*)d_in[2];
  const float* Wk = (const float*)d_in[3];
  const float* bk = (const float*)d_in[4];
  const float* Wv = (const float*)d_in[5];
  const float* bv = (const float*)d_in[6];
  const int* mask = (const int*)d_in[7];
  float* out = (float*)d_out;

  char* ws = (char*)d_ws;
  unsigned short* xb  = (unsigned short*)(ws);             // 4096x768 bf16 (6291456 B)
  unsigned short* wb  = (unsigned short*)(ws + 6291456);   // 3x 768x768 bf16 (3538944 B)
  unsigned short* qw  = (unsigned short*)(ws + 9830400);   // Q (B,H,S,W)
  unsigned short* kw  = (unsigned short*)(ws + 16121856);  // K (B,H,S,W) [pre-relayout]
  unsigned short* vwT = (unsigned short*)(ws + 22413312);  // V^T (B,H,W,S)
  unsigned short* kx  = (unsigned short*)(ws);             // K' frag-major (over xb, dead)
  unsigned short* vx  = (unsigned short*)(ws + 16121856);  // V' frag-major (over kw, dead)

  cvt_all<<<2400, 256, 0, stream>>>(x, Wq, Wk, Wv, xb, wb);
  proj_gemm<<<dim3(32, 18), 256, 0, stream>>>(xb, wb, bq, bk, bv, qw, kw, vwT);
  relayout_kv<<<dim3(16, 24), 256, 0, stream>>>(kw, vwT, kx, vx);
  attn_kernel<<<dim3(32, 24), 256, 0, stream>>>(qw, kx, vx, mask, out);
}

// Round 12
// 84.964 us; speedup vs baseline: 1.0967x; 1.0112x over previous
//
#include <hip/hip_runtime.h>
#include <hip/hip_bf16.h>
#include <stdint.h>

// BERT self-attention fwd: B=2, S=2048, D=768, H=12, W=64. f32 in/out, bf16 MFMA inside.
// Stage 1: cvt x,Wq,Wk,Wv -> bf16.
// Stage 2: QKV projection GEMM (R6 structure): Q/K row-major (B,H,S,W), V^T (B,H,W,S).
// Stage 2.5: relayout_kv: K,V^T -> fragment-major K'/V' (XCD-affine: bh -> XCD bh%8).
// Stage 3: flash attention, barrier-free K-loop, XCD-affine block mapping so each bh's
//   512KB K'/V' is L2-resident on one XCD (fetched from L3 once, read as L2 hits).

typedef __attribute__((ext_vector_type(8))) short bf16x8;    // 8 bf16 = 4 VGPR (MFMA A/B frag)
typedef __attribute__((ext_vector_type(4))) float f32x4;     // 16x16 MFMA C/D frag
typedef __attribute__((ext_vector_type(16))) float f32x16;   // 32x32 MFMA C/D frag
typedef __attribute__((ext_vector_type(8))) unsigned short u16x8;

#define MFMA16(a, b, c) __builtin_amdgcn_mfma_f32_16x16x32_bf16((a), (b), (c), 0, 0, 0)
#define MFMA32(a, b, c) __builtin_amdgcn_mfma_f32_32x32x16_bf16((a), (b), (c), 0, 0, 0)
#define SWZ(row, colb) ((colb) ^ (((row) & 7) << 4))  // 128B-row swizzle

union U32x4BF {
  unsigned u[4];
  bf16x8 v;
};

__device__ __forceinline__ void gl_lds16(const void* g, void* l) {
  __builtin_amdgcn_global_load_lds(
      (__attribute__((address_space(1))) void*)const_cast<void*>(g),
      (__attribute__((address_space(3))) void*)l, 16, 0, 0);
}

__device__ __forceinline__ unsigned short f2bf(float x) {  // RNE f32->bf16
  unsigned int v = __float_as_uint(x);
  return (unsigned short)((v + 0x7fffu + ((v >> 16) & 1u)) >> 16);
}

// ---------------- Stage 1: f32 -> bf16 convert ----------------
__global__ __launch_bounds__(256) void cvt_all(
    const float* __restrict__ x, const float* __restrict__ wq,
    const float* __restrict__ wk, const float* __restrict__ wv,
    unsigned short* __restrict__ xb, unsigned short* __restrict__ wb) {
  int i = blockIdx.x * 256 + threadIdx.x;  // group-of-8 index; total 614400
  const float* s;
  unsigned short* d;
  int off;
  if (i < 393216)      { s = x;  d = xb;            off = i; }
  else if (i < 466944) { s = wq; d = wb;            off = i - 393216; }
  else if (i < 540672) { s = wk; d = wb + 589824;   off = i - 466944; }
  else                 { s = wv; d = wb + 1179648;  off = i - 540672; }
  const float4* sp = (const float4*)s + (size_t)off * 2;
  float4 a = sp[0], b2 = sp[1];
  u16x8 o;
  o[0] = f2bf(a.x); o[1] = f2bf(a.y); o[2] = f2bf(a.z); o[3] = f2bf(a.w);
  o[4] = f2bf(b2.x); o[5] = f2bf(b2.y); o[6] = f2bf(b2.z); o[7] = f2bf(b2.w);
  *((u16x8*)d + off) = o;
}

// ---------------- Stage 2: fused QKV projection (exact R6 structure) ----------------
__global__ __launch_bounds__(256) void proj_gemm(
    const unsigned short* __restrict__ xb, const unsigned short* __restrict__ wb,
    const float* __restrict__ bq, const float* __restrict__ bk, const float* __restrict__ bv,
    unsigned short* __restrict__ qw, unsigned short* __restrict__ kw,
    unsigned short* __restrict__ vw) {
  __shared__ __align__(16) char psmem[49152];  // 3 bufs x (A 8KB | B 8KB)
  const int t = threadIdx.x, lane = t & 63, wave = t >> 6;
  const int lo = lane & 15, hi = lane >> 4;  // hi in 0..3
  const int wr = wave >> 1, wc = wave & 1;   // 2x2 waves, 64x64 each
  const int mbase = blockIdx.x * 128;
  const int wsel = blockIdx.y / 6;
  const int nbase = (blockIdx.y % 6) * 128;
  const char* xc = (const char*)xb;
  const char* wmc = (const char*)(wb + (size_t)wsel * 589824);

  const int pp0 = t * 16, pp1 = t * 16 + 4096;
  const int ar0 = pp0 >> 7, ac0 = (pp0 & 127) ^ ((ar0 & 7) << 4);
  const int am0 = ((ac0 >> 6) << 6) + ar0, ak0 = ac0 & 63;
  const int ar1 = pp1 >> 7, ac1 = (pp1 & 127) ^ ((ar1 & 7) << 4);
  const int am1 = ((ac1 >> 6) << 6) + ar1, ak1 = ac1 & 63;

  const char* xa0 = xc + (size_t)(mbase + am0) * 1536 + ak0;
  const char* xa1 = xc + (size_t)(mbase + am1) * 1536 + ak1;
  const char* wa0 = wmc + (size_t)(nbase + am0) * 1536 + ak0;
  const char* wa1 = wmc + (size_t)(nbase + am1) * 1536 + ak1;

#define PSTAGE(BUF)                              \
  do {                                           \
    char* lb = psmem + (BUF) * 16384;            \
    gl_lds16(xa0, lb + pp0);                     \
    gl_lds16(xa1, lb + pp1);                     \
    gl_lds16(wa0, lb + 8192 + pp0);              \
    gl_lds16(wa1, lb + 8192 + pp1);              \
    xa0 += 64; xa1 += 64; wa0 += 64; wa1 += 64;  \
  } while (0)

  f32x4 acc[4][4];
#pragma unroll
  for (int i = 0; i < 4; i++)
#pragma unroll
    for (int j = 0; j < 4; j++) acc[i][j] = (f32x4){0.f, 0.f, 0.f, 0.f};

  const int axor = (lo & 7) << 4;
  PSTAGE(0);
  PSTAGE(1);
  int cur = 0, sb = 2;
#pragma unroll 1
  for (int it = 0; it < 24; ++it) {
    if (it < 22) {
      PSTAGE(sb);
      asm volatile("s_waitcnt vmcnt(8)" ::: "memory");
    } else if (it == 22) {
      asm volatile("s_waitcnt vmcnt(4)" ::: "memory");
    } else {
      asm volatile("s_waitcnt vmcnt(0)" ::: "memory");
    }
    __builtin_amdgcn_s_barrier();
    const char* lA = psmem + cur * 16384;
    const char* lB = lA + 8192;

    bf16x8 af[4], bf[4];
#pragma unroll
    for (int mf = 0; mf < 4; mf++)
      af[mf] = *(const bf16x8*)(lA + (mf * 16 + lo) * 128 + ((wr * 64 + hi * 16) ^ axor));
#pragma unroll
    for (int nf = 0; nf < 4; nf++)
      bf[nf] = *(const bf16x8*)(lB + (nf * 16 + lo) * 128 + ((wc * 64 + hi * 16) ^ axor));

    __builtin_amdgcn_s_setprio(1);
    if (wsel == 2) {  // V: operand-swapped -> acc holds C^T (rows=n, cols=m)
#pragma unroll
      for (int mf = 0; mf < 4; mf++)
#pragma unroll
        for (int nf = 0; nf < 4; nf++) acc[mf][nf] = MFMA16(bf[nf], af[mf], acc[mf][nf]);
    } else {
#pragma unroll
      for (int mf = 0; mf < 4; mf++)
#pragma unroll
        for (int nf = 0; nf < 4; nf++) acc[mf][nf] = MFMA16(af[mf], bf[nf], acc[mf][nf]);
    }
    __builtin_amdgcn_s_setprio(0);
    __builtin_amdgcn_s_barrier();  // trailing barrier: depth-2 with 3 bufs race-free
    cur = (cur == 2) ? 0 : cur + 1;
    sb = (sb == 2) ? 0 : sb + 1;
  }
#undef PSTAGE

  const float QSCALE = 0.125f * 1.44269504089f;  // fold 1/sqrt(64) * log2(e)
  if (wsel == 2) {
#pragma unroll
    for (int nf = 0; nf < 4; nf++) {
#pragma unroll
      for (int mf = 0; mf < 4; mf++) {
#pragma unroll
        for (int r = 0; r < 4; r++) {
          int n = nbase + wc * 64 + nf * 16 + hi * 4 + r;
          int m = mbase + wr * 64 + mf * 16 + lo;
          int b_ = m >> 11, s = m & 2047;
          int h = n >> 6, wcol = n & 63;
          float val = acc[mf][nf][r] + bv[n];
          vw[(((size_t)b_ * 12 + h) * 64 + wcol) * 2048 + s] = f2bf(val);
        }
      }
    }
  } else {
    const float* bias = (wsel == 0) ? bq : bk;
#pragma unroll
    for (int nf = 0; nf < 4; nf++) {
      int n = nbase + wc * 64 + nf * 16 + lo;
      float bv_ = bias[n];
      int h = n >> 6, wcol = n & 63;
#pragma unroll
      for (int mf = 0; mf < 4; mf++) {
#pragma unroll
        for (int r = 0; r < 4; r++) {
          int m = mbase + wr * 64 + mf * 16 + hi * 4 + r;
          int b_ = m >> 11, s = m & 2047;
          float val = acc[mf][nf][r] + bv_;
          size_t bhh = (size_t)b_ * 12 + h;
          if (wsel == 0)
            qw[(bhh * 2048 + s) * 64 + wcol] = f2bf(val * QSCALE);
          else
            kw[(bhh * 2048 + s) * 64 + wcol] = f2bf(val);
        }
      }
    }
  }
}

// ---------------- Stage 2.5: relayout K,V^T -> fragment-major K',V' ----------------
// grid 384 blocks, XCD-affine: bh -> XCD bh%8 (same mapping as attn) so K'/V' writes land
// in the L2 that attn will read them from. Block handles kts [ktq*4, +4).
__global__ __launch_bounds__(256) void relayout_kv(
    const unsigned short* kw, const unsigned short* __restrict__ vwT,
    unsigned short* __restrict__ kx, unsigned short* vx) {
  __shared__ __align__(16) char rsm[32768];  // [0,16K) K' image | [16K,32K) V' image
  const int t = threadIdx.x;
  const int bid = blockIdx.x;
  const int xcd = bid & 7, sidx = bid >> 3;      // sidx 0..47
  const int bh = xcd + 8 * (sidx % 3);           // bh -> XCD bh%8
  const int ktq = sidx / 3;                      // 0..15
  const size_t bhb = (size_t)bh * 262144;  // per-bh byte stride in all four arrays
  const int kt0 = ktq * 4;

  // K stage: thread reads K[key][d0..d0+8) (16B row-major chunk), writes 16B frag-major LDS
  {
    const int key = t >> 3;      // key-in-tile 0..31
    const int d0 = (t & 7) * 8;  // 0..56
    const char* ksrc = (const char*)kw + bhb + (size_t)kt0 * 4096 + key * 128 + d0 * 2;
    char* kldst = rsm + (d0 >> 4) * 1024 + ((d0 >> 3) & 1) * 512 + key * 16;
#pragma unroll
    for (int c = 0; c < 4; c++)
      *(u16x8*)(kldst + c * 4096) = *(const u16x8*)(ksrc + c * 4096);
  }
  // V stage: thread reads V^T[w][s0..s0+8) (16B s-contiguous), writes 16B frag-major LDS
  {
    const int w = t >> 2;         // 0..63
    const int sl0 = (t & 3) * 8;  // s-in-tile base 0,8,16,24
    const char* vsrc = (const char*)vwT + bhb + (size_t)w * 4096 + (kt0 * 32 + sl0) * 2;
    char* vldst = rsm + 16384 + (w >> 5) * 2048 + ((sl0 >> 4) & 1) * 1024 +
                  ((sl0 >> 3) & 1) * 512 + (w & 31) * 16;
#pragma unroll
    for (int c = 0; c < 4; c++)
      *(u16x8*)(vldst + c * 4096) = *(const u16x8*)(vsrc + c * 64);
  }
  __syncthreads();  // LDS images complete; all this block's kw reads drained

  // copy-out: both images are contiguous 16KB runs of the global arrays
  char* kdst = (char*)kx + bhb + (size_t)ktq * 16384;
  char* vdst = (char*)vx + bhb + (size_t)ktq * 16384;
#pragma unroll
  for (int c = 0; c < 4; c++) {
    int lb = c * 4096 + t * 16;
    *(u16x8*)(kdst + lb) = *(const u16x8*)(rsm + lb);
    *(u16x8*)(vdst + lb) = *(const u16x8*)(rsm + 16384 + lb);
  }
}

// ---------------- Stage 3: flash attention (barrier-free, XCD-affine) ----------------
// grid 768 blocks (flat), XCD-affine decode: all 32 q-blocks of a bh land on XCD bh%8 ->
// that bh's 512KB K'/V' is L2-resident (3 bh x 512KB = 1.5MB per XCD L2).
__global__ __launch_bounds__(256) void attn_kernel(
    const unsigned short* __restrict__ qw, const unsigned short* __restrict__ kx,
    const unsigned short* __restrict__ vx, const int* __restrict__ mask,
    float* __restrict__ out) {
  // [0,16384) epilogue O-staging (2 wq x 8KB) | [16384,16640) ballot bytes |
  // [16640,17152) lsum f32[128]: ((wq*32+q)*2 + wk)
  __shared__ __align__(16) char smem[17152];
  const int t = threadIdx.x, lane = t & 63, wave = t >> 6;
  const int wq = wave >> 1, wk = wave & 1;
  const int l31 = lane & 31, hl = lane >> 5;
  const int bid = blockIdx.x;
  const int xcd = bid & 7, sidx = bid >> 3;   // sidx 0..95
  const int bh = xcd + 8 * (sidx % 3);        // bh -> XCD bh%8
  const int qb = sidx / 3;                    // 0..31
  const int b = bh / 12, hh = bh - b * 12;

  // bit-pack mask: thread t packs keys [t*8, t*8+8) -> ballot bytes
  {
    const int* mb = mask + (size_t)b * 2048 + t * 8;
    int4 a0 = *(const int4*)mb;
    int4 a1 = *(const int4*)(mb + 4);
    unsigned by = (unsigned)(a0.x != 0) | ((unsigned)(a0.y != 0) << 1) |
                  ((unsigned)(a0.z != 0) << 2) | ((unsigned)(a0.w != 0) << 3) |
                  ((unsigned)(a1.x != 0) << 4) | ((unsigned)(a1.y != 0) << 5) |
                  ((unsigned)(a1.z != 0) << 6) | ((unsigned)(a1.w != 0) << 7);
    smem[16384 + t] = (char)by;
  }
  __syncthreads();
  // lane i holds the 32-key ballot of this wave's tile (i&31)
  const unsigned balv = *(const unsigned*)(smem + 16384 + (wk * 32 + l31) * 4);

  // Q B-frags: lane holds Q[q = l31 of wq-half][d = 16s + 8hl + j]
  bf16x8 qv[4];
  {
    int qrow = qb * 64 + wq * 32 + l31;
    const char* qp = (const char*)qw + ((size_t)bh * 2048 + qrow) * 128 + hl * 16;
#pragma unroll
    for (int s = 0; s < 4; s++) qv[s] = *(const bf16x8*)(qp + s * 32);
  }

  // fragment stream pointers (coalesced: lane*16 within 1KB chunks)
  const char* kp = (const char*)kx + (size_t)bh * 262144 + (size_t)wk * 131072 + lane * 16;
  const char* vp = (const char*)vx + (size_t)bh * 262144 + (size_t)wk * 131072 + lane * 16;

  f32x16 oacc[2];
#pragma unroll
  for (int wh = 0; wh < 2; wh++)
#pragma unroll
    for (int g = 0; g < 16; g++) oacc[wh][g] = 0.f;
  float lacc = 0.f;  // per-lane row-sum for q = l31 (this wave's hl/wk slice)

  // prologue: K(0) fragments
  bf16x8 ka0 = *(const bf16x8*)(kp);
  bf16x8 ka1 = *(const bf16x8*)(kp + 1024);
  bf16x8 ka2 = *(const bf16x8*)(kp + 2048);
  bf16x8 ka3 = *(const bf16x8*)(kp + 3072);
  kp += 4096;

#pragma unroll 2
  for (int it = 0; it < 32; ++it) {
    // issue V(it) early (consumed after softmax)
    bf16x8 v00 = *(const bf16x8*)(vp);          // wh0 sp0
    bf16x8 v01 = *(const bf16x8*)(vp + 1024);   // wh0 sp1
    bf16x8 v10 = *(const bf16x8*)(vp + 2048);   // wh1 sp0
    bf16x8 v11 = *(const bf16x8*)(vp + 3072);   // wh1 sp1
    vp += 4096;

    // QK^T swapped: sc[g] = S^T[key-in-tile = (g&3)+8(g>>2)+4hl][q = l31]
    f32x16 sc;
#pragma unroll
    for (int g = 0; g < 16; g++) sc[g] = 0.f;
    __builtin_amdgcn_s_setprio(1);
    sc = MFMA32(ka0, qv[0], sc);
    sc = MFMA32(ka1, qv[1], sc);
    sc = MFMA32(ka2, qv[2], sc);
    sc = MFMA32(ka3, qv[3], sc);
    __builtin_amdgcn_s_setprio(0);

    // prefetch K(it+1); at it=31 this harmlessly reads adjacent valid memory
    ka0 = *(const bf16x8*)(kp);
    ka1 = *(const bf16x8*)(kp + 1024);
    ka2 = *(const bf16x8*)(kp + 2048);
    ka3 = *(const bf16x8*)(kp + 3072);
    kp += 4096;

    // mask (uniform skip when all-ones)
    unsigned bal = __builtin_amdgcn_readlane(balv, it);
    if (bal != 0xFFFFFFFFu) {
#pragma unroll
      for (int g = 0; g < 16; g++) {
        int key = (g & 3) + 8 * (g >> 2) + 4 * hl;
        if (!((bal >> key) & 1)) sc[g] = -30000.f;  // exp2 -> 0
      }
    }

    // P = exp2(sc) in place; pack to bf16 A-frags
#pragma unroll
    for (int g = 0; g < 16; g++) {
      float e_;
      asm("v_exp_f32 %0, %1" : "=v"(e_) : "v"(sc[g]));
      sc[g] = e_;
    }
    unsigned pk[4][2];
#pragma unroll
    for (int m = 0; m < 4; m++) {
      asm("v_cvt_pk_bf16_f32 %0, %1, %2" : "=v"(pk[m][0]) : "v"(sc[4 * m]), "v"(sc[4 * m + 1]));
      asm("v_cvt_pk_bf16_f32 %0, %1, %2" : "=v"(pk[m][1]) : "v"(sc[4 * m + 2]), "v"(sc[4 * m + 3]));
    }
    U32x4BF apv[2];  // A[q=l31][k_local = 16sp + 8hl + j]
#pragma unroll
    for (int sp = 0; sp < 2; sp++)
#pragma unroll
      for (int cp = 0; cp < 2; cp++) {
        unsigned xx = pk[2 * sp][cp], yy = pk[2 * sp + 1][cp];
        asm("v_permlane32_swap_b32 %0, %1" : "+v"(xx), "+v"(yy));
        apv[sp].u[cp] = xx;
        apv[sp].u[2 + cp] = yy;
      }

    // PV: oacc[wh] += P(32q x 32k) @ V(32k x 32w)
    __builtin_amdgcn_s_setprio(1);
    oacc[0] = MFMA32(apv[0].v, v00, oacc[0]);
    oacc[0] = MFMA32(apv[1].v, v01, oacc[0]);
    oacc[1] = MFMA32(apv[0].v, v10, oacc[1]);
    oacc[1] = MFMA32(apv[1].v, v11, oacc[1]);
    __builtin_amdgcn_s_setprio(0);

    // row-sum adds AFTER PV issue: VALU overlaps MFMA pipe (deps: exp results only)
    lacc += (((sc[0] + sc[1]) + (sc[2] + sc[3])) + ((sc[4] + sc[5]) + (sc[6] + sc[7]))) +
            (((sc[8] + sc[9]) + (sc[10] + sc[11])) + ((sc[12] + sc[13]) + (sc[14] + sc[15])));
  }

  // ---- epilogue: cross-wk reduce of O and l, then out = O / l ----
  lacc += __shfl_xor(lacc, 32);  // combine hl halves; all lanes hold sum for q=l31 (wk half)
  if (lane < 32)
    *(float*)(smem + 16640 + (((wq * 32 + l31) << 1) + wk) * 4) = lacc;
  if (wk == 1) {  // partial O as [w][q] f32 into [0,16384)
#pragma unroll
    for (int wh = 0; wh < 2; wh++) {
      int vrow = wh * 32 + l31;
#pragma unroll
      for (int m = 0; m < 4; m++) {
        f32x4 part = (f32x4){oacc[wh][4 * m], oacc[wh][4 * m + 1],
                             oacc[wh][4 * m + 2], oacc[wh][4 * m + 3]};
        *(f32x4*)(smem + wq * 8192 + vrow * 128 + SWZ(vrow, hl * 16 + m * 32)) = part;
      }
    }
  }
  __syncthreads();
  if (wk == 0) {
    float linv[16];
#pragma unroll
    for (int g = 0; g < 16; g++) {
      int qrow = 4 * hl + (g & 3) + 8 * (g >> 2);
      float2 lp = *(const float2*)(smem + 16640 + ((wq * 32 + qrow) << 3));
      linv[g] = __builtin_amdgcn_rcpf(lp.x + lp.y);
    }
#pragma unroll
    for (int wh = 0; wh < 2; wh++) {
      int vrow = wh * 32 + l31;
#pragma unroll
      for (int m = 0; m < 4; m++) {
        f32x4 part = *(const f32x4*)(smem + wq * 8192 + vrow * 128 + SWZ(vrow, hl * 16 + m * 32));
#pragma unroll
        for (int r = 0; r < 4; r++) {
          int g = 4 * m + r;
          int qrow = 4 * hl + r + 8 * m;
          float val = (oacc[wh][g] + part[r]) * linv[g];
          out[((size_t)b * 2048 + qb * 64 + wq * 32 + qrow) * 768 + hh * 64 + wh * 32 + l31] =
              val;
        }
      }
    }
  }
}

// ---------------- launch ----------------
extern "C" void kernel_launch(void* const* d_in, const int* in_sizes, int n_in,
                              void* d_out, int out_size, void* d_ws, size_t ws_size,
                              hipStream_t stream) {
  (void)in_sizes; (void)n_in; (void)out_size; (void)ws_size;
  const float* x  = (const float*)d_in[0];
  const float* Wq = (const float*)d_in[1];
  const float* bq = (const float*)d_in[2];
  const float* Wk = (const float*)d_in[3];
  const float* bk = (const float*)d_in[4];
  const float* Wv = (const float*)d_in[5];
  const float* bv = (const float*)d_in[6];
  const int* mask = (const int*)d_in[7];
  float* out = (float*)d_out;

  char* ws = (char*)d_ws;
  unsigned short* xb  = (unsigned short*)(ws);             // 4096x768 bf16 (6291456 B)
  unsigned short* wb  = (unsigned short*)(ws + 6291456);   // 3x 768x768 bf16 (3538944 B)
  unsigned short* qw  = (unsigned short*)(ws + 9830400);   // Q (B,H,S,W)
  unsigned short* kw  = (unsigned short*)(ws + 16121856);  // K (B,H,S,W) [pre-relayout]
  unsigned short* vwT = (unsigned short*)(ws + 22413312);  // V^T (B,H,W,S)
  unsigned short* kx  = (unsigned short*)(ws);             // K' frag-major (over xb, dead)
  unsigned short* vx  = (unsigned short*)(ws + 16121856);  // V' frag-major (over kw, dead)

  cvt_all<<<2400, 256, 0, stream>>>(x, Wq, Wk, Wv, xb, wb);
  proj_gemm<<<dim3(32, 18), 256, 0, stream>>>(xb, wb, bq, bk, bv, qw, kw, vwT);
  relayout_kv<<<384, 256, 0, stream>>>(kw, vwT, kx, vx);
  attn_kernel<<<768, 256, 0, stream>>>(qw, kx, vx, mask, out);
}